// Round 1
// baseline (348.963 us; speedup 1.0000x reference)
//
#include <hip/hip_runtime.h>
#include <math.h>

#define DM 64
#define NH 4
#define HD 16
#define BATCH 16
#define TSEQ 1024

// ---------------- Kernel 1: fused Q/K/V projections ----------------
// grid = (64 rowblocks, 6 parts). part 0-1: q (x@Wq+bq, scaled 0.25),
// part 2-3: k (enc@Wkv[:, :64]), part 4-5: v (enc@Wkv[:, 64:]).
// Output layout: [b][h][t][16] so the attention kernel's K/V reads are
// wave-uniform contiguous.
__global__ __launch_bounds__(256) void proj_kernel(
    const float* __restrict__ x, const float* __restrict__ enc,
    const float* __restrict__ Wkv, const float* __restrict__ bkv,
    const float* __restrict__ Wq,  const float* __restrict__ bq,
    float* __restrict__ qws, float* __restrict__ kws, float* __restrict__ vws)
{
    const int t = threadIdx.x;
    const int r = blockIdx.x * 256 + t;     // global row 0..16383
    const int b = r >> 10;
    const int trow = r & 1023;
    const int part = blockIdx.y;

    const float* in; const float* W; const float* bias; float* outp;
    int colbase, ldw; float scale;
    if (part < 2)      { in = x;   W = Wq;  ldw = 64;  colbase = part*32;          bias = bq;  outp = qws; scale = 0.25f; }
    else if (part < 4) { in = enc; W = Wkv; ldw = 128; colbase = (part-2)*32;      bias = bkv; outp = kws; scale = 1.0f; }
    else               { in = enc; W = Wkv; ldw = 128; colbase = 64 + (part-4)*32; bias = bkv; outp = vws; scale = 1.0f; }

    // load input row (64 floats) into registers
    float xr[64];
    const float4* inrow = (const float4*)(in + (size_t)r * 64);
    #pragma unroll
    for (int i = 0; i < 16; ++i) {
        float4 v = inrow[i];
        xr[4*i+0] = v.x; xr[4*i+1] = v.y; xr[4*i+2] = v.z; xr[4*i+3] = v.w;
    }

    float acc[32];
    #pragma unroll
    for (int j = 0; j < 32; ++j) acc[j] = bias[colbase + j];   // uniform -> s_load

    #pragma unroll
    for (int i = 0; i < 64; ++i) {
        float xi = xr[i];
        #pragma unroll
        for (int j = 0; j < 32; ++j) acc[j] += xi * W[i*ldw + colbase + j];  // uniform -> s_load
    }
    #pragma unroll
    for (int j = 0; j < 32; ++j) acc[j] *= scale;

    const int hoff = (part < 4) ? colbase : (colbase - 64);     // 0 or 32
    #pragma unroll
    for (int sub = 0; sub < 2; ++sub) {
        int h = (hoff >> 4) + sub;
        float* op = outp + (((size_t)(b*NH + h))*TSEQ + trow)*HD;
        #pragma unroll
        for (int w4 = 0; w4 < 4; ++w4) {
            float4 st;
            st.x = acc[sub*16 + 4*w4+0]; st.y = acc[sub*16 + 4*w4+1];
            st.z = acc[sub*16 + 4*w4+2]; st.w = acc[sub*16 + 4*w4+3];
            ((float4*)op)[w4] = st;
        }
    }
}

// ---------------- Kernel 2: fused flash attention + output projection ----
// grid = (16 q-tiles, 16 batches), 256 threads = 4 waves.
// wave = head (uniform via readfirstlane), lane = q-row within 64-row tile.
// K/V/mask/Wproj addresses are wave-uniform -> scalar loads; inner loops are
// pure v_fma with SGPR second operand. Online softmax in registers.
__global__ __launch_bounds__(256) void attn_kernel(
    const float* __restrict__ qws, const float* __restrict__ kws,
    const float* __restrict__ vws, const int* __restrict__ mask,
    const float* __restrict__ Wproj, const float* __restrict__ bproj,
    float* __restrict__ out)
{
    const int tid = threadIdx.x;
    const int q = tid & 63;
    const int h = __builtin_amdgcn_readfirstlane(tid >> 6);   // force wave-uniform
    const int qt = blockIdx.x;
    const int b  = blockIdx.y;
    const int qrow = qt*64 + q;

    // q fragment (pre-scaled by 1/sqrt(HD))
    float qv[16];
    const float4* qp = (const float4*)(qws + (((size_t)(b*NH + h))*TSEQ + qrow)*HD);
    #pragma unroll
    for (int i = 0; i < 4; ++i) {
        float4 v = qp[i];
        qv[4*i] = v.x; qv[4*i+1] = v.y; qv[4*i+2] = v.z; qv[4*i+3] = v.w;
    }

    const float* kbase = kws + ((size_t)(b*NH + h))*TSEQ*HD;
    const float* vbase = vws + ((size_t)(b*NH + h))*TSEQ*HD;
    const int*   mbase = mask + b*TSEQ;

    float m = -INFINITY, l = 0.0f;
    float ctx[16];
    #pragma unroll
    for (int d = 0; d < 16; ++d) ctx[d] = 0.0f;

    for (int kt = 0; kt < 16; ++kt) {
        const float* kp = kbase + kt*64*HD;
        const float* vp = vbase + kt*64*HD;
        const int*   mp = mbase + kt*64;

        float s[64];
        float tm0 = -INFINITY, tm1 = -INFINITY, tm2 = -INFINITY, tm3 = -INFINITY;
        #pragma unroll
        for (int kj = 0; kj < 64; ++kj) {
            float acc = (mp[kj] == 0) ? -1e30f : 0.0f;   // mask fold (uniform load)
            #pragma unroll
            for (int d = 0; d < 16; ++d) acc += qv[d] * kp[kj*HD + d];
            s[kj] = acc;
            if      ((kj & 3) == 0) tm0 = fmaxf(tm0, acc);
            else if ((kj & 3) == 1) tm1 = fmaxf(tm1, acc);
            else if ((kj & 3) == 2) tm2 = fmaxf(tm2, acc);
            else                    tm3 = fmaxf(tm3, acc);
        }
        float tmax = fmaxf(fmaxf(tm0, tm1), fmaxf(tm2, tm3));
        float mnew = fmaxf(m, tmax);
        float alpha = __expf(m - mnew);    // m=-inf first iter -> alpha=0
        l *= alpha;
        #pragma unroll
        for (int d = 0; d < 16; ++d) ctx[d] *= alpha;

        float l0 = 0.f, l1 = 0.f, l2 = 0.f, l3 = 0.f;
        #pragma unroll
        for (int kj = 0; kj < 64; ++kj) {
            float p = __expf(s[kj] - mnew);
            if      ((kj & 3) == 0) l0 += p;
            else if ((kj & 3) == 1) l1 += p;
            else if ((kj & 3) == 2) l2 += p;
            else                    l3 += p;
            #pragma unroll
            for (int d = 0; d < 16; ++d) ctx[d] += p * vp[kj*HD + d];
        }
        l += (l0 + l1) + (l2 + l3);
        m = mnew;
    }

    // epilogue: normalize, head-mix through LDS (stride 69 -> conflict-free),
    // apply Wproj + bproj
    __shared__ float ctxs[64][69];
    float inv = 1.0f / l;
    #pragma unroll
    for (int d = 0; d < 16; ++d) ctxs[q][h*16 + d] = ctx[d] * inv;
    __syncthreads();

    float o[16];
    #pragma unroll
    for (int j = 0; j < 16; ++j) o[j] = bproj[h*16 + j];     // uniform
    #pragma unroll
    for (int i = 0; i < 64; ++i) {
        float c = ctxs[q][i];
        #pragma unroll
        for (int j = 0; j < 16; ++j) o[j] += c * Wproj[i*64 + h*16 + j];  // uniform
    }

    float* op = out + ((size_t)(b*TSEQ) + qrow)*DM + h*16;
    #pragma unroll
    for (int w4 = 0; w4 < 4; ++w4) {
        float4 st;
        st.x = o[4*w4]; st.y = o[4*w4+1]; st.z = o[4*w4+2]; st.w = o[4*w4+3];
        ((float4*)op)[w4] = st;
    }
}

extern "C" void kernel_launch(void* const* d_in, const int* in_sizes, int n_in,
                              void* d_out, int out_size, void* d_ws, size_t ws_size,
                              hipStream_t stream) {
    const float* x     = (const float*)d_in[0];
    const float* enc   = (const float*)d_in[1];
    const int*   mask  = (const int*)  d_in[2];
    const float* Wkv   = (const float*)d_in[3];
    const float* bkv   = (const float*)d_in[4];
    const float* Wq    = (const float*)d_in[5];
    const float* bq    = (const float*)d_in[6];
    const float* Wproj = (const float*)d_in[7];
    const float* bproj = (const float*)d_in[8];
    float* out = (float*)d_out;

    // workspace: q, k, v each [16][4][1024][16] f32 = 4 MB -> 12 MB total
    float* qws = (float*)d_ws;
    float* kws = qws + (size_t)BATCH*NH*TSEQ*HD;
    float* vws = kws + (size_t)BATCH*NH*TSEQ*HD;

    dim3 blk(256);
    dim3 g1(64, 6);
    proj_kernel<<<g1, blk, 0, stream>>>(x, enc, Wkv, bkv, Wq, bq, qws, kws, vws);
    dim3 g2(16, 16);
    attn_kernel<<<g2, blk, 0, stream>>>(qws, kws, vws, mask, Wproj, bproj, out);
}

// Round 2
// 321.668 us; speedup vs baseline: 1.0849x; 1.0849x over previous
//
#include <hip/hip_runtime.h>
#include <math.h>

#define DM 64
#define NH 4
#define HD 16
#define BATCH 16
#define TSEQ 1024

// ---------------- Kernel 1: fused Q/K/V projections ----------------
// grid = (64 rowblocks, 12 parts), 16 cols/thread. part 0-3: q (x@Wq+bq,
// scaled 0.25), part 4-7: k (enc@Wkv[:, :64]), part 8-11: v (enc@Wkv[:, 64:]).
// Output layout: [b][h][t][16] so attention's K/V reads are wave-uniform.
// 768 blocks -> 12 waves/CU (was 6) for latency hiding.
__global__ __launch_bounds__(256) void proj_kernel(
    const float* __restrict__ x, const float* __restrict__ enc,
    const float* __restrict__ Wkv, const float* __restrict__ bkv,
    const float* __restrict__ Wq,  const float* __restrict__ bq,
    float* __restrict__ qws, float* __restrict__ kws, float* __restrict__ vws)
{
    const int t = threadIdx.x;
    const int r = blockIdx.x * 256 + t;     // global row 0..16383
    const int b = r >> 10;
    const int trow = r & 1023;
    const int part = blockIdx.y;

    const float* in; const float* W; const float* bias; float* outp;
    int colbase, ldw; float scale;
    if (part < 4)      { in = x;   W = Wq;  ldw = 64;  colbase = part*16;          bias = bq;  outp = qws; scale = 0.25f; }
    else if (part < 8) { in = enc; W = Wkv; ldw = 128; colbase = (part-4)*16;      bias = bkv; outp = kws; scale = 1.0f; }
    else               { in = enc; W = Wkv; ldw = 128; colbase = 64 + (part-8)*16; bias = bkv; outp = vws; scale = 1.0f; }

    // load input row (64 floats) into registers
    float xr[64];
    const float4* inrow = (const float4*)(in + (size_t)r * 64);
    #pragma unroll
    for (int i = 0; i < 16; ++i) {
        float4 v = inrow[i];
        xr[4*i+0] = v.x; xr[4*i+1] = v.y; xr[4*i+2] = v.z; xr[4*i+3] = v.w;
    }

    float acc[16];
    #pragma unroll
    for (int j = 0; j < 16; ++j) acc[j] = bias[colbase + j];   // uniform -> s_load

    #pragma unroll
    for (int i = 0; i < 64; ++i) {
        float xi = xr[i];
        #pragma unroll
        for (int j = 0; j < 16; ++j) acc[j] += xi * W[i*ldw + colbase + j];  // uniform -> s_load
    }

    const int hoff = (part < 8) ? colbase : (colbase - 64);
    const int h = hoff >> 4;
    float* op = outp + (((size_t)(b*NH + h))*TSEQ + trow)*HD;
    #pragma unroll
    for (int w4 = 0; w4 < 4; ++w4) {
        float4 st;
        st.x = acc[4*w4+0] * scale; st.y = acc[4*w4+1] * scale;
        st.z = acc[4*w4+2] * scale; st.w = acc[4*w4+3] * scale;
        ((float4*)op)[w4] = st;
    }
}

// ---------------- Kernel 2: fused flash attention + output projection ----
// grid = (16 q-tiles, 16 batches), block = 1024 threads = 16 waves =
// (4 heads x 4 key-quarters). Each wave: online softmax over 256 keys for
// one head, lane = q-row. Partials (m,l,ctx[16]) combine through
// odd-stride-padded LDS (conflict-free). Epilogue Wproj split 4-ways/head.
// K-split gives 4 waves/SIMD for latency hiding (was 1).
__global__ __launch_bounds__(1024) void attn_kernel(
    const float* __restrict__ qws, const float* __restrict__ kws,
    const float* __restrict__ vws, const int* __restrict__ mask,
    const float* __restrict__ Wproj, const float* __restrict__ bproj,
    float* __restrict__ out)
{
    const int tid = threadIdx.x;
    const int q = tid & 63;
    const int wid = __builtin_amdgcn_readfirstlane(tid >> 6);   // 0..15
    const int h  = wid & 3;        // head
    const int ks = wid >> 2;       // key-quarter
    const int qt = blockIdx.x;
    const int b  = blockIdx.y;
    const int qrow = qt*64 + q;

    __shared__ float pm[16][64];
    __shared__ float pl[16][64];
    __shared__ float pctx[16][64][17];   // stride 17 (odd) -> conflict-free
    __shared__ float ctxs[64][69];       // stride 69 (odd) -> conflict-free

    // q fragment (pre-scaled by 1/sqrt(HD) in proj)
    float qv[16];
    const float4* qp = (const float4*)(qws + (((size_t)(b*NH + h))*TSEQ + qrow)*HD);
    #pragma unroll
    for (int i = 0; i < 4; ++i) {
        float4 v = qp[i];
        qv[4*i] = v.x; qv[4*i+1] = v.y; qv[4*i+2] = v.z; qv[4*i+3] = v.w;
    }

    const float* kbase = kws + (((size_t)(b*NH + h))*TSEQ + ks*256)*HD;
    const float* vbase = vws + (((size_t)(b*NH + h))*TSEQ + ks*256)*HD;
    const int*   mbase = mask + b*TSEQ + ks*256;

    float m = -INFINITY, l = 0.0f;
    float ctx[16];
    #pragma unroll
    for (int d = 0; d < 16; ++d) ctx[d] = 0.0f;

    // 8 tiles of 32 keys (32-key tile keeps VGPRs < 128 for 4 waves/SIMD)
    for (int kt = 0; kt < 8; ++kt) {
        const float* kp = kbase + kt*32*HD;
        const float* vp = vbase + kt*32*HD;
        const int*   mp = mbase + kt*32;

        float s[32];
        float tm0 = -INFINITY, tm1 = -INFINITY;
        #pragma unroll
        for (int kj = 0; kj < 32; ++kj) {
            float acc = (mp[kj] == 0) ? -1e30f : 0.0f;   // mask fold (uniform)
            #pragma unroll
            for (int d = 0; d < 16; ++d) acc += qv[d] * kp[kj*HD + d];  // uniform -> s_load
            s[kj] = acc;
            if ((kj & 1) == 0) tm0 = fmaxf(tm0, acc);
            else               tm1 = fmaxf(tm1, acc);
        }
        float mnew = fmaxf(m, fmaxf(tm0, tm1));
        float alpha = __expf(m - mnew);    // m=-inf first iter -> 0
        l *= alpha;
        #pragma unroll
        for (int d = 0; d < 16; ++d) ctx[d] *= alpha;

        float l0 = 0.f, l1 = 0.f;
        #pragma unroll
        for (int kj = 0; kj < 32; ++kj) {
            float p = __expf(s[kj] - mnew);
            if ((kj & 1) == 0) l0 += p; else l1 += p;
            #pragma unroll
            for (int d = 0; d < 16; ++d) ctx[d] += p * vp[kj*HD + d];   // uniform -> s_load
        }
        l += l0 + l1;
        m = mnew;
    }

    // publish partials
    pm[wid][q] = m;
    pl[wid][q] = l;
    #pragma unroll
    for (int d = 0; d < 16; ++d) pctx[wid][q][d] = ctx[d];
    __syncthreads();

    // combine 4 key-quarter partials for head h; this wave handles d-range
    // [ks*4, ks*4+4). Every (h,ks) wave recomputes m*/l* (8 cheap LDS reads).
    {
        float m0 = pm[h][q],    m1 = pm[h+4][q];
        float m2 = pm[h+8][q],  m3 = pm[h+12][q];
        float mstar = fmaxf(fmaxf(m0, m1), fmaxf(m2, m3));
        float e0 = __expf(m0 - mstar), e1 = __expf(m1 - mstar);
        float e2 = __expf(m2 - mstar), e3 = __expf(m3 - mstar);
        float lstar = pl[h][q]*e0 + pl[h+4][q]*e1 + pl[h+8][q]*e2 + pl[h+12][q]*e3;
        float inv = 1.0f / lstar;
        #pragma unroll
        for (int dd = 0; dd < 4; ++dd) {
            int d = ks*4 + dd;
            float c = pctx[h][q][d]*e0 + pctx[h+4][q][d]*e1
                    + pctx[h+8][q][d]*e2 + pctx[h+12][q][d]*e3;
            ctxs[q][h*16 + d] = c * inv;
        }
    }
    __syncthreads();

    // epilogue: head-mix + Wproj. Wave (h,ks) computes out cols
    // [h*16+ks*4, h*16+ks*4+4) for its 64 q-rows.
    const int colb = h*16 + ks*4;
    float o[4];
    #pragma unroll
    for (int j = 0; j < 4; ++j) o[j] = bproj[colb + j];          // uniform
    #pragma unroll
    for (int i = 0; i < 64; ++i) {
        float c = ctxs[q][i];
        #pragma unroll
        for (int j = 0; j < 4; ++j) o[j] += c * Wproj[i*64 + colb + j];  // uniform
    }

    float4 st; st.x = o[0]; st.y = o[1]; st.z = o[2]; st.w = o[3];
    *((float4*)(out + ((size_t)(b*TSEQ) + qrow)*DM + colb)) = st;
}

extern "C" void kernel_launch(void* const* d_in, const int* in_sizes, int n_in,
                              void* d_out, int out_size, void* d_ws, size_t ws_size,
                              hipStream_t stream) {
    const float* x     = (const float*)d_in[0];
    const float* enc   = (const float*)d_in[1];
    const int*   mask  = (const int*)  d_in[2];
    const float* Wkv   = (const float*)d_in[3];
    const float* bkv   = (const float*)d_in[4];
    const float* Wq    = (const float*)d_in[5];
    const float* bq    = (const float*)d_in[6];
    const float* Wproj = (const float*)d_in[7];
    const float* bproj = (const float*)d_in[8];
    float* out = (float*)d_out;

    // workspace: q, k, v each [16][4][1024][16] f32 = 4 MB -> 12 MB total
    float* qws = (float*)d_ws;
    float* kws = qws + (size_t)BATCH*NH*TSEQ*HD;
    float* vws = kws + (size_t)BATCH*NH*TSEQ*HD;

    dim3 g1(64, 12);
    proj_kernel<<<g1, dim3(256), 0, stream>>>(x, enc, Wkv, bkv, Wq, bq, qws, kws, vws);
    dim3 g2(16, 16);
    attn_kernel<<<g2, dim3(1024), 0, stream>>>(qws, kws, vws, mask, Wproj, bproj, out);
}

// Round 3
// 119.925 us; speedup vs baseline: 2.9098x; 2.6822x over previous
//
#include <hip/hip_runtime.h>
#include <hip/hip_bf16.h>
#include <math.h>

#define DM 64
#define NH 4
#define HD 16
#define BATCH 16
#define TSEQ 1024

typedef short bf16x8 __attribute__((ext_vector_type(8)));
typedef float f32x4  __attribute__((ext_vector_type(4)));
typedef float f32x16 __attribute__((ext_vector_type(16)));

__device__ inline short f2bf(float x) {
    __hip_bfloat16 h = __float2bfloat16(x);
    return __builtin_bit_cast(short, h);
}
__device__ inline float bf2f(short s) {
    __hip_bfloat16 h = __builtin_bit_cast(__hip_bfloat16, s);
    return __bfloat162float(h);
}

// ---------------- Kernel 1: fused Q/K/V projections -> bf16 (hi/lo) --------
// grid = (64 rowblocks, 12 parts), 256 thr. parts 0-3: q (scaled by
// 0.25*log2e, hi/lo split), 4-7: k (hi/lo), 8-11: v -> transposed vt[d][key].
// W slice staged in LDS (broadcast ds_reads; avoids SMEM lgkmcnt(0) drains).
__global__ __launch_bounds__(256) void proj_kernel(
    const float* __restrict__ x, const float* __restrict__ enc,
    const float* __restrict__ Wkv, const float* __restrict__ bkv,
    const float* __restrict__ Wq,  const float* __restrict__ bq,
    short* __restrict__ qhi, short* __restrict__ qlo,
    short* __restrict__ khi, short* __restrict__ klo,
    short* __restrict__ vt)
{
    const int t = threadIdx.x;
    const int r = blockIdx.x * 256 + t;     // global row 0..16383
    const int b = r >> 10;
    const int trow = r & 1023;
    const int part = blockIdx.y;

    const float* in; const float* W; const float* bias;
    int cb, ldw;
    if (part < 4)      { in = x;   W = Wq;  ldw = 64;  cb = part*16;          bias = bq;  }
    else if (part < 8) { in = enc; W = Wkv; ldw = 128; cb = (part-4)*16;      bias = bkv; }
    else               { in = enc; W = Wkv; ldw = 128; cb = 64 + (part-8)*16; bias = bkv; }

    __shared__ float wsl[64][17];
    for (int idx = t; idx < 1024; idx += 256)
        wsl[idx >> 4][idx & 15] = W[(idx >> 4)*ldw + cb + (idx & 15)];
    __syncthreads();

    float xr[64];
    const float4* inrow = (const float4*)(in + (size_t)r * 64);
    #pragma unroll
    for (int i = 0; i < 16; ++i) {
        float4 v = inrow[i];
        xr[4*i+0]=v.x; xr[4*i+1]=v.y; xr[4*i+2]=v.z; xr[4*i+3]=v.w;
    }

    float acc[16];
    #pragma unroll
    for (int j = 0; j < 16; ++j) acc[j] = bias[cb + j];
    #pragma unroll
    for (int i = 0; i < 64; ++i) {
        float xi = xr[i];
        #pragma unroll
        for (int j = 0; j < 16; ++j) acc[j] += xi * wsl[i][j];
    }

    if (part < 8) {
        // q: fold softmax scale AND log2(e) so attn uses exp2 directly
        const float scale = (part < 4) ? 0.36067376022224085f : 1.0f;
        bf16x8 h0, h1, l0, l1;
        #pragma unroll
        for (int j = 0; j < 16; ++j) {
            float v = acc[j] * scale;
            short hb = f2bf(v);
            short lb = f2bf(v - bf2f(hb));
            if (j < 8) { h0[j] = hb; l0[j] = lb; }
            else       { h1[j-8] = hb; l1[j-8] = lb; }
        }
        const int h = cb >> 4;   // cb < 64 for both q and k parts
        short* dh; short* dl;
        if (part < 4) { dh = qhi; dl = qlo; } else { dh = khi; dl = klo; }
        size_t off = (((size_t)(b*NH + h))*TSEQ + trow)*HD;
        *(bf16x8*)(dh + off)     = h0;
        *(bf16x8*)(dh + off + 8) = h1;
        *(bf16x8*)(dl + off)     = l0;
        *(bf16x8*)(dl + off + 8) = l1;
    } else {
        // vt[b][h][d][key] bf16; per-d stores are coalesced across threads
        const int h = part - 8;
        short* base = vt + ((size_t)(b*NH + h)) * HD * TSEQ;
        #pragma unroll
        for (int j = 0; j < 16; ++j)
            base[(size_t)j * TSEQ + trow] = f2bf(acc[j]);
    }
}

// ---------------- Kernel 2: MFMA flash attention + Wproj epilogue ----------
// grid = (32 q-tiles of 32 rows, 16 batches), 512 thr = 8 waves =
// (4 heads x 2 key-halves). Per step (32 keys):
//   S[32q,32k] = 3x mfma_32x32x16_bf16 (q/k hi-lo)  [B-frags: coalesced 1KB]
//   p = exp2(S) (no-max softmax; scale*log2e pre-folded), mask via cndmask
//   P -> per-wave LDS (f32, no barrier) -> A-frags (bf16)
//   ctx += 2x mfma_16x16x32_bf16 with B from transposed vt  [b128 loads]
// Partials (l, ctx) combine across key-halves in LDS; epilogue does Wproj.
__global__ __launch_bounds__(512) void attn_kernel(
    const short* __restrict__ qhi, const short* __restrict__ qlo,
    const short* __restrict__ khi, const short* __restrict__ klo,
    const short* __restrict__ vt,  const int* __restrict__ mask,
    const float* __restrict__ Wproj, const float* __restrict__ bproj,
    float* __restrict__ out)
{
    const int tid  = threadIdx.x;
    const int lane = tid & 63;
    const int wid  = __builtin_amdgcn_readfirstlane(tid >> 6);  // 0..7
    const int h  = wid & 3;
    const int ks = wid >> 2;          // key half
    const int qt = blockIdx.x;        // 0..31
    const int b  = blockIdx.y;
    const int qbase = qt * 32;

    __shared__ float Pbuf[8][32][36];   // stride 36 f32: 16B-aligned rows
    __shared__ float Cbuf[2][32][68];
    __shared__ float Lbuf[2][NH][32];

    const int l31  = lane & 31;
    const int l15  = lane & 15;
    const int half = lane >> 5;       // 0/1
    const int quad = lane >> 4;       // 0..3

    // Q A-frags (32x32x16): A[m=l31][k=half*8+j]
    const size_t qoff = (((size_t)(b*NH + h))*TSEQ + qbase + l31)*HD + half*8;
    const bf16x8 qAh = *(const bf16x8*)(qhi + qoff);
    const bf16x8 qAl = *(const bf16x8*)(qlo + qoff);

    const short* khb = khi + (((size_t)(b*NH + h))*TSEQ + ks*512)*HD;
    const short* klb = klo + (((size_t)(b*NH + h))*TSEQ + ks*512)*HD;
    const short* vtb = vt  + ((size_t)(b*NH + h))*HD*TSEQ + ks*512;
    const int*  mrow = mask + b*TSEQ + ks*512;

    f32x4 ctx0, ctx1;
    #pragma unroll
    for (int i = 0; i < 4; ++i) { ctx0[i] = 0.f; ctx1[i] = 0.f; }
    float lacc[16];
    #pragma unroll
    for (int i = 0; i < 16; ++i) lacc[i] = 0.f;

    float* pmine = &Pbuf[wid][0][0];

    for (int step = 0; step < 16; ++step) {
        const int koff = step * 32;
        // K B-frags: B[k=half*8+j][n=key=l31] = K[koff+l31][half*8+j]
        const bf16x8 kBh = *(const bf16x8*)(khb + (size_t)(koff + l31)*HD + half*8);
        const bf16x8 kBl = *(const bf16x8*)(klb + (size_t)(koff + l31)*HD + half*8);

        f32x16 S;
        #pragma unroll
        for (int i = 0; i < 16; ++i) S[i] = 0.f;
        S = __builtin_amdgcn_mfma_f32_32x32x16_bf16(qAh, kBh, S, 0, 0, 0);
        S = __builtin_amdgcn_mfma_f32_32x32x16_bf16(qAh, kBl, S, 0, 0, 0);
        S = __builtin_amdgcn_mfma_f32_32x32x16_bf16(qAl, kBh, S, 0, 0, 0);

        const int mk = mrow[koff + l31];   // this lane's key column
        #pragma unroll
        for (int i = 0; i < 16; ++i) {
            float p = __builtin_amdgcn_exp2f(S[i]);
            p = (mk != 0) ? p : 0.0f;
            lacc[i] += p;
            const int row = (i & 3) + 8*(i >> 2) + 4*half;  // 32x32 C/D row
            pmine[row*36 + l31] = p;
        }
        // same-wave LDS write->read: lgkmcnt ordering only, no barrier

        // PV A-frags: A[m=q=l15][k=quad*8+j] (f32 LDS -> bf16)
        const float* pr0 = &Pbuf[wid][l15][quad*8];
        const float* pr1 = &Pbuf[wid][16 + l15][quad*8];
        bf16x8 pA0, pA1;
        #pragma unroll
        for (int j = 0; j < 8; ++j) { pA0[j] = f2bf(pr0[j]); pA1[j] = f2bf(pr1[j]); }

        // V B-frag: B[k=quad*8+j][n=d=l15] = vt[d][koff+quad*8+j]
        const bf16x8 vB = *(const bf16x8*)(vtb + (size_t)l15*TSEQ + koff + quad*8);

        ctx0 = __builtin_amdgcn_mfma_f32_16x16x32_bf16(pA0, vB, ctx0, 0, 0, 0);
        ctx1 = __builtin_amdgcn_mfma_f32_16x16x32_bf16(pA1, vB, ctx1, 0, 0, 0);
    }

    // l: sum over the 32 key columns (lanes) of this wave
    #pragma unroll
    for (int off = 1; off < 32; off <<= 1) {
        #pragma unroll
        for (int i = 0; i < 16; ++i)
            lacc[i] += __shfl_xor(lacc[i], off, 64);
    }
    if (l31 == 0) {
        #pragma unroll
        for (int i = 0; i < 16; ++i) {
            const int row = (i & 3) + 8*(i >> 2) + 4*half;
            Lbuf[ks][h][row] = lacc[i];
        }
    }

    // ctx partial -> Cbuf (16x16 C/D: row=quad*4+r, col=l15)
    #pragma unroll
    for (int rr = 0; rr < 4; ++rr) {
        Cbuf[ks][quad*4 + rr][h*HD + l15]      = ctx0[rr];
        Cbuf[ks][16 + quad*4 + rr][h*HD + l15] = ctx1[rr];
    }
    __syncthreads();

    // epilogue: thread -> (q=tid>>4, 4 out cols); combine key-halves,
    // normalize per head, apply Wproj + bproj
    const int q  = tid >> 4;         // 0..31
    const int cbo = (tid & 15) * 4;  // 0..60
    float linv[NH];
    #pragma unroll
    for (int hh = 0; hh < NH; ++hh)
        linv[hh] = 1.0f / (Lbuf[0][hh][q] + Lbuf[1][hh][q]);

    float o0 = bproj[cbo], o1 = bproj[cbo+1], o2 = bproj[cbo+2], o3 = bproj[cbo+3];
    #pragma unroll
    for (int i = 0; i < 64; ++i) {
        float cv = (Cbuf[0][q][i] + Cbuf[1][q][i]) * linv[i >> 4];
        const float* wr = Wproj + i*DM + cbo;
        o0 += cv*wr[0]; o1 += cv*wr[1]; o2 += cv*wr[2]; o3 += cv*wr[3];
    }
    float4 st; st.x = o0; st.y = o1; st.z = o2; st.w = o3;
    *(float4*)(out + ((size_t)b*TSEQ + qbase + q)*DM + cbo) = st;
}

extern "C" void kernel_launch(void* const* d_in, const int* in_sizes, int n_in,
                              void* d_out, int out_size, void* d_ws, size_t ws_size,
                              hipStream_t stream) {
    const float* x     = (const float*)d_in[0];
    const float* enc   = (const float*)d_in[1];
    const int*   mask  = (const int*)  d_in[2];
    const float* Wkv   = (const float*)d_in[3];
    const float* bkv   = (const float*)d_in[4];
    const float* Wq    = (const float*)d_in[5];
    const float* bq    = (const float*)d_in[6];
    const float* Wproj = (const float*)d_in[7];
    const float* bproj = (const float*)d_in[8];
    float* out = (float*)d_out;

    // ws: qhi,qlo,khi,klo ([16][4][1024][16] bf16 = 2MB each) + vt (2MB) = 10MB
    const size_t SZ = (size_t)BATCH*NH*TSEQ*HD;
    short* qhi = (short*)d_ws;
    short* qlo = qhi + SZ;
    short* khi = qlo + SZ;
    short* klo = khi + SZ;
    short* vt  = klo + SZ;

    proj_kernel<<<dim3(64, 12), dim3(256), 0, stream>>>(
        x, enc, Wkv, bkv, Wq, bq, qhi, qlo, khi, klo, vt);
    attn_kernel<<<dim3(32, 16), dim3(512), 0, stream>>>(
        qhi, qlo, khi, klo, vt, mask, Wproj, bproj, out);
}